// Round 5
// baseline (363.616 us; speedup 1.0000x reference)
//
#include <hip/hip_runtime.h>
#include <hip/hip_bf16.h>
#include <stdint.h>

typedef __bf16 bf16;
typedef __attribute__((ext_vector_type(8))) __bf16 bf16x8;
typedef __attribute__((ext_vector_type(4))) float f32x4;

constexpr int Bn = 4, Tn = 2048, Cn = 1024, Hn = 16, HD = 64;
constexpr int Mn = Bn * Tn; // 8192

__device__ __forceinline__ void gl_lds16(const void* g, void* l) {
  __builtin_amdgcn_global_load_lds(
      (const __attribute__((address_space(1))) void*)g,
      (__attribute__((address_space(3))) void*)l, 16u, 0, 0u);
}

// ---------------- x (fp32) -> bf16 ----------------
__global__ __launch_bounds__(256) void k_cvt_x(const float* __restrict__ x,
                                               bf16* __restrict__ xb) {
  int i = (blockIdx.x * 256 + threadIdx.x) * 8;
  float4 a = *(const float4*)(x + i);
  float4 b = *(const float4*)(x + i + 4);
  bf16x8 v;
  v[0] = (bf16)a.x; v[1] = (bf16)a.y; v[2] = (bf16)a.z; v[3] = (bf16)a.w;
  v[4] = (bf16)b.x; v[5] = (bf16)b.y; v[6] = (bf16)b.z; v[7] = (bf16)b.w;
  *(bf16x8*)(xb + i) = v;
}

// ---------------- W [K][N] fp32 -> WT [N][K] bf16 ----------------
__global__ __launch_bounds__(256) void k_tw(const float* __restrict__ W0,
                                            const float* __restrict__ W1,
                                            const float* __restrict__ W2,
                                            const float* __restrict__ W3,
                                            bf16* __restrict__ WT) {
  __shared__ float tile[32][33];
  const float* W = (blockIdx.z == 0) ? W0 : (blockIdx.z == 1) ? W1
                  : (blockIdx.z == 2) ? W2 : W3;
  bf16* out = WT + (size_t)blockIdx.z * Cn * Cn;
  int tx = threadIdx.x & 31, ty = threadIdx.x >> 5;  // 32 x 8
  int gx = blockIdx.x * 32 + tx;   // n
  int gy = blockIdx.y * 32;        // k
#pragma unroll
  for (int j = 0; j < 32; j += 8)
    tile[ty + j][tx] = W[(size_t)(gy + ty + j) * Cn + gx];
  __syncthreads();
  int ox = blockIdx.y * 32 + tx;   // k
  int oy = blockIdx.x * 32;        // n
#pragma unroll
  for (int j = 0; j < 32; j += 8)
    out[(size_t)(oy + ty + j) * Cn + ox] = (bf16)tile[tx][ty + j];
}

// ---------------- GEMM: out[M,N] = A[M,K] @ BT[N,K]^T + bias ----------------
// MODE 0: out bf16, written headed [B][H][T][64], value (acc+bias)*scale
// MODE 1: out fp32, written flat [M][C]  (d_out is float32!)
template <int MODE, typename OutT>
__global__ __launch_bounds__(256) void k_gemm(const bf16* __restrict__ A,
                                              const bf16* __restrict__ BT,
                                              const float* __restrict__ bias,
                                              OutT* __restrict__ out,
                                              float scale) {
  constexpr int KD = 1024;
  __shared__ __align__(16) bf16 As[128 * 64];
  __shared__ __align__(16) bf16 Bs[128 * 64];
  const int t = threadIdx.x;
  const int w = t >> 6, l = t & 63;
  const int m0 = blockIdx.y * 128, n0 = blockIdx.x * 128;
  const int wr = (w >> 1) * 64, wc = (w & 1) * 64;
  f32x4 acc[4][4] = {};

  for (int kt = 0; kt < KD; kt += 64) {
    __syncthreads();
#pragma unroll
    for (int i = 0; i < 4; ++i) {
      int c = i * 256 + t;
      int row = c >> 3;
      int seg = (c & 7) ^ (row & 7);  // inverse-swizzled source (rule #21)
      gl_lds16(A + (size_t)(m0 + row) * KD + kt + seg * 8,
               (char*)As + i * 4096 + w * 1024);
      gl_lds16(BT + (size_t)(n0 + row) * KD + kt + seg * 8,
               (char*)Bs + i * 4096 + w * 1024);
    }
    __syncthreads();
#pragma unroll
    for (int kc = 0; kc < 2; ++kc) {
      bf16x8 af[4], bg[4];
#pragma unroll
      for (int mi = 0; mi < 4; ++mi) {
        int row = wr + mi * 16 + (l & 15);
        int off = (row * 128 + kc * 64 + (l >> 4) * 16) ^ ((row & 7) << 4);
        af[mi] = *(const bf16x8*)((const char*)As + off);
      }
#pragma unroll
      for (int ni = 0; ni < 4; ++ni) {
        int row = wc + ni * 16 + (l & 15);
        int off = (row * 128 + kc * 64 + (l >> 4) * 16) ^ ((row & 7) << 4);
        bg[ni] = *(const bf16x8*)((const char*)Bs + off);
      }
#pragma unroll
      for (int mi = 0; mi < 4; ++mi)
#pragma unroll
        for (int ni = 0; ni < 4; ++ni)
          acc[mi][ni] = __builtin_amdgcn_mfma_f32_16x16x32_bf16(
              af[mi], bg[ni], acc[mi][ni], 0, 0, 0);
    }
  }
  // epilogue: C/D layout col = l&15, row = (l>>4)*4 + r
#pragma unroll
  for (int ni = 0; ni < 4; ++ni) {
    int col = n0 + wc + ni * 16 + (l & 15);
    float bv = bias[col];
#pragma unroll
    for (int mi = 0; mi < 4; ++mi) {
#pragma unroll
      for (int r = 0; r < 4; ++r) {
        int row = m0 + wr + mi * 16 + (l >> 4) * 4 + r;
        float v = (acc[mi][ni][r] + bv) * scale;
        size_t idx;
        if (MODE == 0) {
          int bb = row >> 11, tt = row & 2047, hh = col >> 6, dd = col & 63;
          idx = ((size_t)(bb * Hn + hh) * Tn + tt) * HD + dd;
        } else {
          idx = (size_t)row * Cn + col;
        }
        out[idx] = (OutT)v;
      }
    }
  }
}

// ---------------- flash attention (causal) ----------------
// Q,K,V: [B][H][T][64] bf16 (Q pre-scaled by 1/8). Y: [B*T][C] bf16.
__global__ __launch_bounds__(256) void k_attn(const bf16* __restrict__ Q,
                                              const bf16* __restrict__ K,
                                              const bf16* __restrict__ V,
                                              bf16* __restrict__ Y) {
  __shared__ __align__(16) bf16 Ks[64 * 64];
  __shared__ __align__(16) bf16 Vt[64 * 64];      // V^T [d][kv], swizzled
  __shared__ __align__(16) bf16 Ps[4 * 16 * 64];  // per-wave P, swizzled
  const int t = threadIdx.x, w = t >> 6, l = t & 63;
  const int qtile = blockIdx.x, bh = blockIdx.y;
  const size_t base = (size_t)bh * Tn * HD;
  const bf16* Qh = Q + base;
  const bf16* Kh = K + base;
  const bf16* Vh = V + base;
  const int qbase = qtile * 64 + w * 16;

  bf16x8 aq[2];
#pragma unroll
  for (int kc = 0; kc < 2; ++kc)
    aq[kc] = *(const bf16x8*)(Qh + (size_t)(qbase + (l & 15)) * HD + kc * 32 +
                              (l >> 4) * 8);

  f32x4 yacc[4] = {};
  float m_[4], l_[4];
#pragma unroll
  for (int r = 0; r < 4; ++r) { m_[r] = -1e30f; l_[r] = 0.f; }
  const int q_row = qbase + (l >> 4) * 4;  // + r

  for (int kv0 = 0; kv0 <= qtile * 64; kv0 += 64) {
    __syncthreads();
    // stage K tile (inverse-swizzled source -> linear LDS)
#pragma unroll
    for (int i = 0; i < 2; ++i) {
      int c = i * 256 + t;
      int row = c >> 3, seg = (c & 7) ^ (row & 7);
      gl_lds16(Kh + (size_t)(kv0 + row) * HD + seg * 8,
               (char*)Ks + i * 4096 + w * 1024);
    }
    // stage V^T with per-lane scatter (regular stores), swizzled layout
#pragma unroll
    for (int i = 0; i < 2; ++i) {
      int seg = w + i * 4;
      bf16x8 vv = *(const bf16x8*)(Vh + (size_t)(kv0 + l) * HD + seg * 8);
#pragma unroll
      for (int j = 0; j < 8; ++j) {
        int d = seg * 8 + j;
        int byte = (d * 128 + l * 2) ^ ((d & 7) << 4);
        *(bf16*)((char*)Vt + byte) = vv[j];
      }
    }
    __syncthreads();
    // QK^T
    f32x4 s[4] = {};
#pragma unroll
    for (int nj = 0; nj < 4; ++nj) {
#pragma unroll
      for (int kc = 0; kc < 2; ++kc) {
        int row = nj * 16 + (l & 15);
        int off = (row * 128 + kc * 64 + (l >> 4) * 16) ^ ((row & 7) << 4);
        bf16x8 bk = *(const bf16x8*)((const char*)Ks + off);
        s[nj] = __builtin_amdgcn_mfma_f32_16x16x32_bf16(aq[kc], bk, s[nj], 0, 0, 0);
      }
    }
    // causal mask + row max
    float pm[4];
#pragma unroll
    for (int r = 0; r < 4; ++r) pm[r] = -1e30f;
#pragma unroll
    for (int nj = 0; nj < 4; ++nj) {
      int kv_g = kv0 + nj * 16 + (l & 15);
#pragma unroll
      for (int r = 0; r < 4; ++r) {
        if (kv_g > q_row + r) s[nj][r] = -1e30f;
        pm[r] = fmaxf(pm[r], s[nj][r]);
      }
    }
#pragma unroll
    for (int r = 0; r < 4; ++r)
#pragma unroll
      for (int sh = 1; sh < 16; sh <<= 1)
        pm[r] = fmaxf(pm[r], __shfl_xor(pm[r], sh, 64));
    float fac[4], rs[4];
#pragma unroll
    for (int r = 0; r < 4; ++r) {
      float mn = fmaxf(m_[r], pm[r]);
      fac[r] = __expf(m_[r] - mn);
      m_[r] = mn;
      rs[r] = 0.f;
    }
    // P = exp(s-m): row sum + write to per-wave swizzled LDS
#pragma unroll
    for (int nj = 0; nj < 4; ++nj) {
#pragma unroll
      for (int r = 0; r < 4; ++r) {
        float p = __expf(s[nj][r] - m_[r]);
        rs[r] += p;
        int qrl = (l >> 4) * 4 + r;
        int byte = (qrl * 128 + (nj * 16 + (l & 15)) * 2) ^ ((qrl & 7) << 4);
        *(bf16*)((char*)Ps + w * 2048 + byte) = (bf16)p;
      }
    }
#pragma unroll
    for (int r = 0; r < 4; ++r) {
#pragma unroll
      for (int sh = 1; sh < 16; sh <<= 1) rs[r] += __shfl_xor(rs[r], sh, 64);
      l_[r] = l_[r] * fac[r] + rs[r];
    }
#pragma unroll
    for (int ni = 0; ni < 4; ++ni)
#pragma unroll
      for (int r = 0; r < 4; ++r) yacc[ni][r] *= fac[r];
    // PV (own-wave Ps; compiler tracks the LDS dependency)
#pragma unroll
    for (int kc = 0; kc < 2; ++kc) {
      int rowp = l & 15;
      int offp = ((rowp * 128 + kc * 64 + (l >> 4) * 16) ^ ((rowp & 7) << 4)) +
                 w * 2048;
      bf16x8 pa = *(const bf16x8*)((const char*)Ps + offp);
#pragma unroll
      for (int ni = 0; ni < 4; ++ni) {
        int row = ni * 16 + (l & 15);
        int off = (row * 128 + kc * 64 + (l >> 4) * 16) ^ ((row & 7) << 4);
        bf16x8 bv = *(const bf16x8*)((const char*)Vt + off);
        yacc[ni] = __builtin_amdgcn_mfma_f32_16x16x32_bf16(pa, bv, yacc[ni], 0, 0, 0);
      }
    }
  }
  // write y into flat [M][C] with col = h*64+d
  const int hh = bh & 15, bb = bh >> 4;
#pragma unroll
  for (int ni = 0; ni < 4; ++ni) {
    int d = ni * 16 + (l & 15);
#pragma unroll
    for (int r = 0; r < 4; ++r) {
      int qg = qbase + (l >> 4) * 4 + r;
      float v = yacc[ni][r] / l_[r];
      Y[(size_t)(bb * Tn + qg) * Cn + hh * HD + d] = (bf16)v;
    }
  }
}

extern "C" void kernel_launch(void* const* d_in, const int* in_sizes, int n_in,
                              void* d_out, int out_size, void* d_ws,
                              size_t ws_size, hipStream_t stream) {
  const float* x  = (const float*)d_in[0];
  const float* Wq = (const float*)d_in[1];
  const float* bq = (const float*)d_in[2];
  const float* Wk = (const float*)d_in[3];
  const float* bk = (const float*)d_in[4];
  const float* Wv = (const float*)d_in[5];
  const float* bv = (const float*)d_in[6];
  const float* Wo = (const float*)d_in[7];
  const float* bo = (const float*)d_in[8];
  char* ws = (char*)d_ws;
  bf16* xb = (bf16*)ws;                          // 16MB, reused as y
  bf16* WT = (bf16*)(ws + (size_t)(16 << 20));   // 8MB (4 x 1M elems)
  bf16* Qh = (bf16*)(ws + (size_t)(24 << 20));   // 16MB
  bf16* Kh = (bf16*)(ws + (size_t)(40 << 20));   // 16MB
  bf16* Vh = (bf16*)(ws + (size_t)(56 << 20));   // 16MB
  float* out = (float*)d_out;                    // reference output is fp32

  k_cvt_x<<<4096, 256, 0, stream>>>(x, xb);
  k_tw<<<dim3(32, 32, 4), 256, 0, stream>>>(Wq, Wk, Wv, Wo, WT);
  k_gemm<0, bf16><<<dim3(8, 64), 256, 0, stream>>>(xb, WT, bq, Qh, 0.125f);
  k_gemm<0, bf16><<<dim3(8, 64), 256, 0, stream>>>(xb, WT + (1u << 20), bk, Kh, 1.0f);
  k_gemm<0, bf16><<<dim3(8, 64), 256, 0, stream>>>(xb, WT + (2u << 20), bv, Vh, 1.0f);
  k_attn<<<dim3(32, 64), 256, 0, stream>>>(Qh, Kh, Vh, xb);
  k_gemm<1, float><<<dim3(8, 64), 256, 0, stream>>>(xb, WT + (3u << 20), bo, out, 1.0f);
}

// Round 6
// 201.431 us; speedup vs baseline: 1.8052x; 1.8052x over previous
//
#include <hip/hip_runtime.h>
#include <hip/hip_bf16.h>
#include <stdint.h>

typedef __bf16 bf16;
typedef __attribute__((ext_vector_type(8))) __bf16 bf16x8;
typedef __attribute__((ext_vector_type(4))) __bf16 bf16x4;
typedef __attribute__((ext_vector_type(4))) float f32x4;

constexpr int Bn = 4, Tn = 2048, Cn = 1024, Hn = 16, HD = 64;
constexpr int Mn = Bn * Tn; // 8192

__device__ __forceinline__ void gl_lds16(const void* g, void* l) {
  __builtin_amdgcn_global_load_lds(
      (const __attribute__((address_space(1))) void*)g,
      (__attribute__((address_space(3))) void*)l, 16u, 0, 0u);
}

// ---------------- x (fp32) -> bf16 ----------------
__global__ __launch_bounds__(256) void k_cvt_x(const float* __restrict__ x,
                                               bf16* __restrict__ xb) {
  int i = (blockIdx.x * 256 + threadIdx.x) * 8;
  float4 a = *(const float4*)(x + i);
  float4 b = *(const float4*)(x + i + 4);
  bf16x8 v;
  v[0] = (bf16)a.x; v[1] = (bf16)a.y; v[2] = (bf16)a.z; v[3] = (bf16)a.w;
  v[4] = (bf16)b.x; v[5] = (bf16)b.y; v[6] = (bf16)b.z; v[7] = (bf16)b.w;
  *(bf16x8*)(xb + i) = v;
}

// ---------------- W [K][N] fp32 -> WT [N][K] bf16 ----------------
__global__ __launch_bounds__(256) void k_tw(const float* __restrict__ W0,
                                            const float* __restrict__ W1,
                                            const float* __restrict__ W2,
                                            const float* __restrict__ W3,
                                            bf16* __restrict__ WT) {
  __shared__ float tile[32][33];
  const float* W = (blockIdx.z == 0) ? W0 : (blockIdx.z == 1) ? W1
                  : (blockIdx.z == 2) ? W2 : W3;
  bf16* out = WT + (size_t)blockIdx.z * Cn * Cn;
  int tx = threadIdx.x & 31, ty = threadIdx.x >> 5;  // 32 x 8
  int gx = blockIdx.x * 32 + tx;   // n
  int gy = blockIdx.y * 32;        // k
#pragma unroll
  for (int j = 0; j < 32; j += 8)
    tile[ty + j][tx] = W[(size_t)(gy + ty + j) * Cn + gx];
  __syncthreads();
  int ox = blockIdx.y * 32 + tx;   // k
  int oy = blockIdx.x * 32;        // n
#pragma unroll
  for (int j = 0; j < 32; j += 8)
    out[(size_t)(oy + ty + j) * Cn + ox] = (bf16)tile[tx][ty + j];
}

// ---------------- GEMM: out[M,N] = A[M,K] @ BT[N,K]^T + bias ----------------
// MODE 0: out bf16, written headed [B][H][T][64], value (acc+bias)*scale
// MODE 1: out fp32, written flat [M][C]  (d_out is float32)
template <int MODE, typename OutT>
__global__ __launch_bounds__(256) void k_gemm(const bf16* __restrict__ A,
                                              const bf16* __restrict__ BT,
                                              const float* __restrict__ bias,
                                              OutT* __restrict__ out,
                                              float scale) {
  constexpr int KD = 1024;
  __shared__ __align__(16) bf16 As[128 * 64];
  __shared__ __align__(16) bf16 Bs[128 * 64];
  const int t = threadIdx.x;
  const int w = t >> 6, l = t & 63;
  const int m0 = blockIdx.y * 128, n0 = blockIdx.x * 128;
  const int wr = (w >> 1) * 64, wc = (w & 1) * 64;
  f32x4 acc[4][4] = {};

  for (int kt = 0; kt < KD; kt += 64) {
    __syncthreads();
#pragma unroll
    for (int i = 0; i < 4; ++i) {
      int c = i * 256 + t;
      int row = c >> 3;
      int seg = (c & 7) ^ (row & 7);  // inverse-swizzled source (rule #21)
      gl_lds16(A + (size_t)(m0 + row) * KD + kt + seg * 8,
               (char*)As + i * 4096 + w * 1024);
      gl_lds16(BT + (size_t)(n0 + row) * KD + kt + seg * 8,
               (char*)Bs + i * 4096 + w * 1024);
    }
    __syncthreads();
#pragma unroll
    for (int kc = 0; kc < 2; ++kc) {
      bf16x8 af[4], bg[4];
#pragma unroll
      for (int mi = 0; mi < 4; ++mi) {
        int row = wr + mi * 16 + (l & 15);
        int off = (row * 128 + kc * 64 + (l >> 4) * 16) ^ ((row & 7) << 4);
        af[mi] = *(const bf16x8*)((const char*)As + off);
      }
#pragma unroll
      for (int ni = 0; ni < 4; ++ni) {
        int row = wc + ni * 16 + (l & 15);
        int off = (row * 128 + kc * 64 + (l >> 4) * 16) ^ ((row & 7) << 4);
        bg[ni] = *(const bf16x8*)((const char*)Bs + off);
      }
#pragma unroll
      for (int mi = 0; mi < 4; ++mi)
#pragma unroll
        for (int ni = 0; ni < 4; ++ni)
          acc[mi][ni] = __builtin_amdgcn_mfma_f32_16x16x32_bf16(
              af[mi], bg[ni], acc[mi][ni], 0, 0, 0);
    }
  }
  // epilogue: C/D layout col = l&15, row = (l>>4)*4 + r
#pragma unroll
  for (int ni = 0; ni < 4; ++ni) {
    int col = n0 + wc + ni * 16 + (l & 15);
    float bv = bias[col];
#pragma unroll
    for (int mi = 0; mi < 4; ++mi) {
#pragma unroll
      for (int r = 0; r < 4; ++r) {
        int row = m0 + wr + mi * 16 + (l >> 4) * 4 + r;
        float v = (acc[mi][ni][r] + bv) * scale;
        size_t idx;
        if (MODE == 0) {
          int bb = row >> 11, tt = row & 2047, hh = col >> 6, dd = col & 63;
          idx = ((size_t)(bb * Hn + hh) * Tn + tt) * HD + dd;
        } else {
          idx = (size_t)row * Cn + col;
        }
        out[idx] = (OutT)v;
      }
    }
  }
}

// ---------------- flash attention (causal), swapped-operand form ----------
// Q,K,V: [B][H][T][64] bf16 (Q pre-scaled by 1/8). Y: [B*T][C] bf16.
// Grid: 1D 2048 blocks. bh = wg&63 (low bits -> XCD pinning: all q-tiles of
// one head land on one XCD so K/V stay in its L2). qtile reversed so the
// heavy (long-causal-range) blocks dispatch first.
// Swapped QK^T: s[nj] = mfma(K_frag, Q_frag) -> D col (l&15) = q, row = k.
// Each lane owns ONE q-row: softmax is in-lane (15-op tree + 2 shuffles),
// m/l are scalars, P stays in registers (no P LDS round-trip).
// Swapped PV: yacc[ni] = mfma(Vt_frag, P_frag) -> D col = q (matches m/l),
// row = d. A/B share a lane-local virtual-k permutation
// k_act(g,j) = (2*vkc + (j>>2))*16 + g*4 + (j&3)  -- valid because MFMA
// pairs A-slot (g,j) with B-slot (g,j) (proved by round-1 correctness).
__global__ __launch_bounds__(256) void k_attn(const bf16* __restrict__ Q,
                                              const bf16* __restrict__ K,
                                              const bf16* __restrict__ V,
                                              bf16* __restrict__ Y) {
  __shared__ __align__(16) bf16 Ks[64 * 64];
  __shared__ __align__(16) bf16 Vt[64 * 64];  // V^T [d][kv], swizzled
  const int t = threadIdx.x, w = t >> 6, l = t & 63;
  const int g = l >> 4, q16 = l & 15;
  const int wg = blockIdx.x;
  const int bh = wg & 63;
  const int qtile = (Tn / 64 - 1) - (wg >> 6);  // heavy tiles first
  const size_t base = (size_t)bh * Tn * HD;
  const bf16* Qh = Q + base;
  const bf16* Kh = K + base;
  const bf16* Vh = V + base;
  const int qbase = qtile * 64 + w * 16;
  const int qg = qbase + q16;  // this lane's q row (within head)

  bf16x8 aq[2];
#pragma unroll
  for (int kc = 0; kc < 2; ++kc)
    aq[kc] = *(const bf16x8*)(Qh + (size_t)qg * HD + kc * 32 + g * 8);

  f32x4 yacc[4] = {};
  float m_ = -1e30f, l_ = 0.f;

  for (int kv0 = 0; kv0 <= qtile * 64; kv0 += 64) {
    __syncthreads();
    // stage K tile (inverse-swizzled source -> linear LDS)
#pragma unroll
    for (int i = 0; i < 2; ++i) {
      int c = i * 256 + t;
      int row = c >> 3, seg = (c & 7) ^ (row & 7);
      gl_lds16(Kh + (size_t)(kv0 + row) * HD + seg * 8,
               (char*)Ks + i * 4096 + w * 1024);
    }
    // stage V^T (per-lane scatter, swizzled layout)
#pragma unroll
    for (int i = 0; i < 2; ++i) {
      int seg = w + i * 4;
      bf16x8 vv = *(const bf16x8*)(Vh + (size_t)(kv0 + l) * HD + seg * 8);
#pragma unroll
      for (int j = 0; j < 8; ++j) {
        int d = seg * 8 + j;
        int byte = (d * 128 + l * 2) ^ ((d & 7) << 4);
        *(bf16*)((char*)Vt + byte) = vv[j];
      }
    }
    __syncthreads();
    // QK^T swapped: lane (g,q16) holds S[k = nj*16 + g*4 + r][q = q16]
    f32x4 s[4] = {};
#pragma unroll
    for (int nj = 0; nj < 4; ++nj) {
#pragma unroll
      for (int kc = 0; kc < 2; ++kc) {
        int row = nj * 16 + q16;
        int off = (row * 128 + kc * 64 + g * 16) ^ ((row & 7) << 4);
        bf16x8 ak = *(const bf16x8*)((const char*)Ks + off);
        s[nj] = __builtin_amdgcn_mfma_f32_16x16x32_bf16(ak, aq[kc], s[nj], 0, 0, 0);
      }
    }
    // causal mask (only near the diagonal; wave-uniform branch)
    if (kv0 + 63 > qbase) {
#pragma unroll
      for (int nj = 0; nj < 4; ++nj)
#pragma unroll
        for (int r = 0; r < 4; ++r)
          if (kv0 + nj * 16 + g * 4 + r > qg) s[nj][r] = -1e30f;
    }
    // in-lane row max + 2-shuffle reduce across the 4 lane-groups of q
    float mx = fmaxf(fmaxf(fmaxf(s[0][0], s[0][1]), fmaxf(s[0][2], s[0][3])),
                     fmaxf(fmaxf(s[1][0], s[1][1]), fmaxf(s[1][2], s[1][3])));
    mx = fmaxf(mx,
               fmaxf(fmaxf(fmaxf(s[2][0], s[2][1]), fmaxf(s[2][2], s[2][3])),
                     fmaxf(fmaxf(s[3][0], s[3][1]), fmaxf(s[3][2], s[3][3]))));
    mx = fmaxf(mx, __shfl_xor(mx, 16));
    mx = fmaxf(mx, __shfl_xor(mx, 32));
    float mn = fmaxf(m_, mx);
    float fac = __expf(m_ - mn);
    m_ = mn;
    float rs = 0.f;
#pragma unroll
    for (int nj = 0; nj < 4; ++nj)
#pragma unroll
      for (int r = 0; r < 4; ++r) {
        float p = __expf(s[nj][r] - mn);
        s[nj][r] = p;
        rs += p;
      }
    rs += __shfl_xor(rs, 16);
    rs += __shfl_xor(rs, 32);
    l_ = l_ * fac + rs;
#pragma unroll
    for (int ni = 0; ni < 4; ++ni)
#pragma unroll
      for (int r = 0; r < 4; ++r) yacc[ni][r] *= fac;
    // PV swapped: yacc[ni] -> Y[d = ni*16 + g*4 + r][q = q16]
#pragma unroll
    for (int vkc = 0; vkc < 2; ++vkc) {
      bf16x8 pb;
#pragma unroll
      for (int j = 0; j < 4; ++j) {
        pb[j] = (bf16)s[2 * vkc][j];
        pb[4 + j] = (bf16)s[2 * vkc + 1][j];
      }
#pragma unroll
      for (int ni = 0; ni < 4; ++ni) {
        int d = ni * 16 + q16;
        int b0 = (d * 128 + vkc * 64 + g * 8) ^ ((d & 7) << 4);
        int b1 = (d * 128 + vkc * 64 + 32 + g * 8) ^ ((d & 7) << 4);
        bf16x4 lo = *(const bf16x4*)((const char*)Vt + b0);
        bf16x4 hi = *(const bf16x4*)((const char*)Vt + b1);
        bf16x8 va;
#pragma unroll
        for (int j = 0; j < 4; ++j) { va[j] = lo[j]; va[4 + j] = hi[j]; }
        yacc[ni] = __builtin_amdgcn_mfma_f32_16x16x32_bf16(va, pb, yacc[ni], 0, 0, 0);
      }
    }
  }
  // epilogue: lane owns q = qg; d = ni*16 + g*4 + r (contiguous in r)
  const int hh = bh & 15, bb = bh >> 4;
  float inv = 1.f / l_;
#pragma unroll
  for (int ni = 0; ni < 4; ++ni) {
    bf16x4 o;
#pragma unroll
    for (int r = 0; r < 4; ++r) o[r] = (bf16)(yacc[ni][r] * inv);
    int d0 = ni * 16 + g * 4;
    *(bf16x4*)&Y[(size_t)(bb * Tn + qg) * Cn + hh * HD + d0] = o;
  }
}

extern "C" void kernel_launch(void* const* d_in, const int* in_sizes, int n_in,
                              void* d_out, int out_size, void* d_ws,
                              size_t ws_size, hipStream_t stream) {
  const float* x  = (const float*)d_in[0];
  const float* Wq = (const float*)d_in[1];
  const float* bq = (const float*)d_in[2];
  const float* Wk = (const float*)d_in[3];
  const float* bk = (const float*)d_in[4];
  const float* Wv = (const float*)d_in[5];
  const float* bv = (const float*)d_in[6];
  const float* Wo = (const float*)d_in[7];
  const float* bo = (const float*)d_in[8];
  char* ws = (char*)d_ws;
  bf16* xb = (bf16*)ws;                          // 16MB, reused as y
  bf16* WT = (bf16*)(ws + (size_t)(16 << 20));   // 8MB (4 x 1M elems)
  bf16* Qh = (bf16*)(ws + (size_t)(24 << 20));   // 16MB
  bf16* Kh = (bf16*)(ws + (size_t)(40 << 20));   // 16MB
  bf16* Vh = (bf16*)(ws + (size_t)(56 << 20));   // 16MB
  float* out = (float*)d_out;                    // reference output is fp32

  k_cvt_x<<<4096, 256, 0, stream>>>(x, xb);
  k_tw<<<dim3(32, 32, 4), 256, 0, stream>>>(Wq, Wk, Wv, Wo, WT);
  k_gemm<0, bf16><<<dim3(8, 64), 256, 0, stream>>>(xb, WT, bq, Qh, 0.125f);
  k_gemm<0, bf16><<<dim3(8, 64), 256, 0, stream>>>(xb, WT + (1u << 20), bk, Kh, 1.0f);
  k_gemm<0, bf16><<<dim3(8, 64), 256, 0, stream>>>(xb, WT + (2u << 20), bv, Vh, 1.0f);
  k_attn<<<2048, 256, 0, stream>>>(Qh, Kh, Vh, xb);
  k_gemm<1, float><<<dim3(8, 64), 256, 0, stream>>>(xb, WT + (3u << 20), bo, out, 1.0f);
}

// Round 7
// 198.517 us; speedup vs baseline: 1.8317x; 1.0147x over previous
//
#include <hip/hip_runtime.h>
#include <hip/hip_bf16.h>
#include <stdint.h>

typedef __bf16 bf16;
typedef __attribute__((ext_vector_type(8))) __bf16 bf16x8;
typedef __attribute__((ext_vector_type(4))) __bf16 bf16x4;
typedef __attribute__((ext_vector_type(4))) float f32x4;

constexpr int Bn = 4, Tn = 2048, Cn = 1024, Hn = 16, HD = 64;
constexpr int Mn = Bn * Tn; // 8192

__device__ __forceinline__ void gl_lds16(const void* g, void* l) {
  __builtin_amdgcn_global_load_lds(
      (const __attribute__((address_space(1))) void*)g,
      (__attribute__((address_space(3))) void*)l, 16u, 0, 0u);
}

// ---------------- x (fp32) -> bf16 ----------------
__global__ __launch_bounds__(256) void k_cvt_x(const float* __restrict__ x,
                                               bf16* __restrict__ xb) {
  int i = (blockIdx.x * 256 + threadIdx.x) * 8;
  float4 a = *(const float4*)(x + i);
  float4 b = *(const float4*)(x + i + 4);
  bf16x8 v;
  v[0] = (bf16)a.x; v[1] = (bf16)a.y; v[2] = (bf16)a.z; v[3] = (bf16)a.w;
  v[4] = (bf16)b.x; v[5] = (bf16)b.y; v[6] = (bf16)b.z; v[7] = (bf16)b.w;
  *(bf16x8*)(xb + i) = v;
}

// ---------------- W [K][N] fp32 -> WT [N][K] bf16 ----------------
__global__ __launch_bounds__(256) void k_tw(const float* __restrict__ W0,
                                            const float* __restrict__ W1,
                                            const float* __restrict__ W2,
                                            const float* __restrict__ W3,
                                            bf16* __restrict__ WT) {
  __shared__ float tile[32][33];
  const float* W = (blockIdx.z == 0) ? W0 : (blockIdx.z == 1) ? W1
                  : (blockIdx.z == 2) ? W2 : W3;
  bf16* out = WT + (size_t)blockIdx.z * Cn * Cn;
  int tx = threadIdx.x & 31, ty = threadIdx.x >> 5;  // 32 x 8
  int gx = blockIdx.x * 32 + tx;   // n
  int gy = blockIdx.y * 32;        // k
#pragma unroll
  for (int j = 0; j < 32; j += 8)
    tile[ty + j][tx] = W[(size_t)(gy + ty + j) * Cn + gx];
  __syncthreads();
  int ox = blockIdx.y * 32 + tx;   // k
  int oy = blockIdx.x * 32;        // n
#pragma unroll
  for (int j = 0; j < 32; j += 8)
    out[(size_t)(oy + ty + j) * Cn + ox] = (bf16)tile[tx][ty + j];
}

// ---------------- GEMM: out[M,N] = A[M,K] @ BT[N,K]^T + bias ----------------
template <int MODE, typename OutT>
__global__ __launch_bounds__(256) void k_gemm(const bf16* __restrict__ A,
                                              const bf16* __restrict__ BT,
                                              const float* __restrict__ bias,
                                              OutT* __restrict__ out,
                                              float scale) {
  constexpr int KD = 1024;
  __shared__ __align__(16) bf16 As[128 * 64];
  __shared__ __align__(16) bf16 Bs[128 * 64];
  const int t = threadIdx.x;
  const int w = t >> 6, l = t & 63;
  const int m0 = blockIdx.y * 128, n0 = blockIdx.x * 128;
  const int wr = (w >> 1) * 64, wc = (w & 1) * 64;
  f32x4 acc[4][4] = {};

  for (int kt = 0; kt < KD; kt += 64) {
    __syncthreads();
#pragma unroll
    for (int i = 0; i < 4; ++i) {
      int c = i * 256 + t;
      int row = c >> 3;
      int seg = (c & 7) ^ (row & 7);  // inverse-swizzled source (rule #21)
      gl_lds16(A + (size_t)(m0 + row) * KD + kt + seg * 8,
               (char*)As + i * 4096 + w * 1024);
      gl_lds16(BT + (size_t)(n0 + row) * KD + kt + seg * 8,
               (char*)Bs + i * 4096 + w * 1024);
    }
    __syncthreads();
#pragma unroll
    for (int kc = 0; kc < 2; ++kc) {
      bf16x8 af[4], bg[4];
#pragma unroll
      for (int mi = 0; mi < 4; ++mi) {
        int row = wr + mi * 16 + (l & 15);
        int off = (row * 128 + kc * 64 + (l >> 4) * 16) ^ ((row & 7) << 4);
        af[mi] = *(const bf16x8*)((const char*)As + off);
      }
#pragma unroll
      for (int ni = 0; ni < 4; ++ni) {
        int row = wc + ni * 16 + (l & 15);
        int off = (row * 128 + kc * 64 + (l >> 4) * 16) ^ ((row & 7) << 4);
        bg[ni] = *(const bf16x8*)((const char*)Bs + off);
      }
#pragma unroll
      for (int mi = 0; mi < 4; ++mi)
#pragma unroll
        for (int ni = 0; ni < 4; ++ni)
          acc[mi][ni] = __builtin_amdgcn_mfma_f32_16x16x32_bf16(
              af[mi], bg[ni], acc[mi][ni], 0, 0, 0);
    }
  }
#pragma unroll
  for (int ni = 0; ni < 4; ++ni) {
    int col = n0 + wc + ni * 16 + (l & 15);
    float bv = bias[col];
#pragma unroll
    for (int mi = 0; mi < 4; ++mi) {
#pragma unroll
      for (int r = 0; r < 4; ++r) {
        int row = m0 + wr + mi * 16 + (l >> 4) * 4 + r;
        float v = (acc[mi][ni][r] + bv) * scale;
        size_t idx;
        if (MODE == 0) {
          int bb = row >> 11, tt = row & 2047, hh = col >> 6, dd = col & 63;
          idx = ((size_t)(bb * Hn + hh) * Tn + tt) * HD + dd;
        } else {
          idx = (size_t)row * Cn + col;
        }
        out[idx] = (OutT)v;
      }
    }
  }
}

// ---------------- flash attention (causal), swapped-operand + dbuf ----------
// Q,K,V: [B][H][T][64] bf16 (Q pre-scaled by 1/8). Y: [B*T][C] bf16.
// Vt layout L ("PV-fragment order"): element (kv,d) at byte
//   d*128 + inner(kv) ^ ((d&7)<<4),
//   inner(kv) = (kv>>5)*64 + ((kv&15)>>2)*16 + (((kv>>4)&1)*4 + (kv&3))*2
// so the PV A-fragment (vkc,ni) is ONE b128 read at
//   (d*128 + vkc*64 + g*16) ^ ((d&7)<<4)  -- same bank pattern as QK reads.
// Double-buffered K/V: 1 barrier per KV-iter; next tile's K gl_lds + V
// global loads issued right after the barrier (hide under softmax+PV),
// V LDS write after PV (targets the other buffer -> no extra barrier).
__global__ __launch_bounds__(256) void k_attn(const bf16* __restrict__ Q,
                                              const bf16* __restrict__ K,
                                              const bf16* __restrict__ V,
                                              bf16* __restrict__ Y) {
  __shared__ __align__(16) bf16 Ks[2][64 * 64];
  __shared__ __align__(16) bf16 Vt[2][64 * 64];
  const int t = threadIdx.x, w = t >> 6, l = t & 63;
  const int g = l >> 4, q16 = l & 15;
  const int wg = blockIdx.x;
  const int bh = wg & 63;                        // low bits -> XCD pinning
  const int qtile = (Tn / 64 - 1) - (wg >> 6);   // heavy tiles first
  const size_t base = (size_t)bh * Tn * HD;
  const bf16* Qh = Q + base;
  const bf16* Kh = K + base;
  const bf16* Vh = V + base;
  const int qbase = qtile * 64 + w * 16;
  const int qg = qbase + q16;

  bf16x8 aq[2];
#pragma unroll
  for (int kc = 0; kc < 2; ++kc)
    aq[kc] = *(const bf16x8*)(Qh + (size_t)qg * HD + kc * 32 + g * 8);

  // layout-L per-lane inner byte offset (kv = l)
  const int innerL = (l >> 5) * 64 + ((l & 15) >> 2) * 16 +
                     (((l >> 4) & 1) * 4 + (l & 3)) * 2;

  f32x4 yacc[4] = {};
  float m_ = -1e30f, l_ = 0.f;

  // prologue: stage tile 0 -> buf 0
#pragma unroll
  for (int i = 0; i < 2; ++i) {
    int c = i * 256 + t;
    int row = c >> 3, seg = (c & 7) ^ (row & 7);
    gl_lds16(Kh + (size_t)row * HD + seg * 8,
             (char*)Ks[0] + i * 4096 + w * 1024);
  }
#pragma unroll
  for (int i = 0; i < 2; ++i) {
    int seg = w + i * 4;
    bf16x8 vv = *(const bf16x8*)(Vh + (size_t)l * HD + seg * 8);
#pragma unroll
    for (int j = 0; j < 8; ++j) {
      int d = seg * 8 + j;
      *(bf16*)((char*)Vt[0] + ((d * 128 + innerL) ^ ((d & 7) << 4))) = vv[j];
    }
  }

  int p = 0;
  for (int kv0 = 0; kv0 <= qtile * 64; kv0 += 64) {
    __syncthreads();  // buf p staged (drains gl_lds + ds_writes of all waves)
    const bool more = kv0 + 64 <= qtile * 64;
    bf16x8 vv0, vv1;
    if (more) {  // issue next-tile loads EARLY (latency hides under compute)
#pragma unroll
      for (int i = 0; i < 2; ++i) {
        int c = i * 256 + t;
        int row = c >> 3, seg = (c & 7) ^ (row & 7);
        gl_lds16(Kh + (size_t)(kv0 + 64 + row) * HD + seg * 8,
                 (char*)Ks[p ^ 1] + i * 4096 + w * 1024);
      }
      vv0 = *(const bf16x8*)(Vh + (size_t)(kv0 + 64 + l) * HD + w * 8);
      vv1 = *(const bf16x8*)(Vh + (size_t)(kv0 + 64 + l) * HD + (w + 4) * 8);
    }
    // QK^T swapped: lane (g,q16) holds S[k = nj*16 + g*4 + r][q = q16]
    f32x4 s[4] = {};
    __builtin_amdgcn_s_setprio(1);
#pragma unroll
    for (int nj = 0; nj < 4; ++nj) {
#pragma unroll
      for (int kc = 0; kc < 2; ++kc) {
        int row = nj * 16 + q16;
        int off = (row * 128 + kc * 64 + g * 16) ^ ((row & 7) << 4);
        bf16x8 ak = *(const bf16x8*)((const char*)Ks[p] + off);
        s[nj] = __builtin_amdgcn_mfma_f32_16x16x32_bf16(ak, aq[kc], s[nj], 0, 0, 0);
      }
    }
    __builtin_amdgcn_s_setprio(0);
    // causal mask (wave-uniform branch, only near diagonal)
    if (kv0 + 63 > qbase) {
#pragma unroll
      for (int nj = 0; nj < 4; ++nj)
#pragma unroll
        for (int r = 0; r < 4; ++r)
          if (kv0 + nj * 16 + g * 4 + r > qg) s[nj][r] = -1e30f;
    }
    // in-lane softmax (15-op max tree + 2 shuffles)
    float mx = fmaxf(fmaxf(fmaxf(s[0][0], s[0][1]), fmaxf(s[0][2], s[0][3])),
                     fmaxf(fmaxf(s[1][0], s[1][1]), fmaxf(s[1][2], s[1][3])));
    mx = fmaxf(mx,
               fmaxf(fmaxf(fmaxf(s[2][0], s[2][1]), fmaxf(s[2][2], s[2][3])),
                     fmaxf(fmaxf(s[3][0], s[3][1]), fmaxf(s[3][2], s[3][3]))));
    mx = fmaxf(mx, __shfl_xor(mx, 16));
    mx = fmaxf(mx, __shfl_xor(mx, 32));
    float mn = fmaxf(m_, mx);
    float fac = __expf(m_ - mn);
    m_ = mn;
    float rs = 0.f;
#pragma unroll
    for (int nj = 0; nj < 4; ++nj)
#pragma unroll
      for (int r = 0; r < 4; ++r) {
        float pv = __expf(s[nj][r] - mn);
        s[nj][r] = pv;
        rs += pv;
      }
    rs += __shfl_xor(rs, 16);
    rs += __shfl_xor(rs, 32);
    l_ = l_ * fac + rs;
#pragma unroll
    for (int ni = 0; ni < 4; ++ni)
#pragma unroll
      for (int r = 0; r < 4; ++r) yacc[ni][r] *= fac;
    // PV: fragment = ONE b128 read from layout-L Vt (QK-identical bank pattern)
    __builtin_amdgcn_s_setprio(1);
#pragma unroll
    for (int vkc = 0; vkc < 2; ++vkc) {
      bf16x8 pb;
#pragma unroll
      for (int j = 0; j < 4; ++j) {
        pb[j] = (bf16)s[2 * vkc][j];
        pb[4 + j] = (bf16)s[2 * vkc + 1][j];
      }
#pragma unroll
      for (int ni = 0; ni < 4; ++ni) {
        int d = ni * 16 + q16;
        int off = (d * 128 + vkc * 64 + g * 16) ^ ((d & 7) << 4);
        bf16x8 va = *(const bf16x8*)((const char*)Vt[p] + off);
        yacc[ni] = __builtin_amdgcn_mfma_f32_16x16x32_bf16(va, pb, yacc[ni], 0, 0, 0);
      }
    }
    __builtin_amdgcn_s_setprio(0);
    // write next V tile late (other buffer -> race-free without barrier)
    if (more) {
#pragma unroll
      for (int j = 0; j < 8; ++j) {
        int d = w * 8 + j;
        *(bf16*)((char*)Vt[p ^ 1] + ((d * 128 + innerL) ^ ((d & 7) << 4))) = vv0[j];
      }
#pragma unroll
      for (int j = 0; j < 8; ++j) {
        int d = (w + 4) * 8 + j;
        *(bf16*)((char*)Vt[p ^ 1] + ((d * 128 + innerL) ^ ((d & 7) << 4))) = vv1[j];
      }
    }
    p ^= 1;
  }
  // epilogue: lane owns q = qg; d = ni*16 + g*4 + r (contiguous in r)
  const int hh = bh & 15, bb = bh >> 4;
  float inv = 1.f / l_;
#pragma unroll
  for (int ni = 0; ni < 4; ++ni) {
    bf16x4 o;
#pragma unroll
    for (int r = 0; r < 4; ++r) o[r] = (bf16)(yacc[ni][r] * inv);
    int d0 = ni * 16 + g * 4;
    *(bf16x4*)&Y[(size_t)(bb * Tn + qg) * Cn + hh * HD + d0] = o;
  }
}

extern "C" void kernel_launch(void* const* d_in, const int* in_sizes, int n_in,
                              void* d_out, int out_size, void* d_ws,
                              size_t ws_size, hipStream_t stream) {
  const float* x  = (const float*)d_in[0];
  const float* Wq = (const float*)d_in[1];
  const float* bq = (const float*)d_in[2];
  const float* Wk = (const float*)d_in[3];
  const float* bk = (const float*)d_in[4];
  const float* Wv = (const float*)d_in[5];
  const float* bv = (const float*)d_in[6];
  const float* Wo = (const float*)d_in[7];
  const float* bo = (const float*)d_in[8];
  char* ws = (char*)d_ws;
  bf16* xb = (bf16*)ws;                          // 16MB, reused as y
  bf16* WT = (bf16*)(ws + (size_t)(16 << 20));   // 8MB (4 x 1M elems)
  bf16* Qh = (bf16*)(ws + (size_t)(24 << 20));   // 16MB
  bf16* Kh = (bf16*)(ws + (size_t)(40 << 20));   // 16MB
  bf16* Vh = (bf16*)(ws + (size_t)(56 << 20));   // 16MB
  float* out = (float*)d_out;                    // reference output is fp32

  k_cvt_x<<<4096, 256, 0, stream>>>(x, xb);
  k_tw<<<dim3(32, 32, 4), 256, 0, stream>>>(Wq, Wk, Wv, Wo, WT);
  k_gemm<0, bf16><<<dim3(8, 64), 256, 0, stream>>>(xb, WT, bq, Qh, 0.125f);
  k_gemm<0, bf16><<<dim3(8, 64), 256, 0, stream>>>(xb, WT + (1u << 20), bk, Kh, 1.0f);
  k_gemm<0, bf16><<<dim3(8, 64), 256, 0, stream>>>(xb, WT + (2u << 20), bv, Vh, 1.0f);
  k_attn<<<2048, 256, 0, stream>>>(Qh, Kh, Vh, xb);
  k_gemm<1, float><<<dim3(8, 64), 256, 0, stream>>>(xb, WT + (3u << 20), bo, out, 1.0f);
}

// Round 8
// 175.749 us; speedup vs baseline: 2.0690x; 1.1295x over previous
//
#include <hip/hip_runtime.h>
#include <hip/hip_bf16.h>
#include <stdint.h>

typedef __bf16 bf16;
typedef __attribute__((ext_vector_type(8))) __bf16 bf16x8;
typedef __attribute__((ext_vector_type(4))) __bf16 bf16x4;
typedef __attribute__((ext_vector_type(4))) float f32x4;

constexpr int Bn = 4, Tn = 2048, Cn = 1024, Hn = 16, HD = 64;
constexpr int Mn = Bn * Tn; // 8192

__device__ __forceinline__ void gl_lds16(const void* g, void* l) {
  __builtin_amdgcn_global_load_lds(
      (const __attribute__((address_space(1))) void*)g,
      (__attribute__((address_space(3))) void*)l, 16u, 0, 0u);
}

// ---------------- x (fp32) -> bf16 ----------------
__global__ __launch_bounds__(256) void k_cvt_x(const float* __restrict__ x,
                                               bf16* __restrict__ xb) {
  int i = (blockIdx.x * 256 + threadIdx.x) * 8;
  float4 a = *(const float4*)(x + i);
  float4 b = *(const float4*)(x + i + 4);
  bf16x8 v;
  v[0] = (bf16)a.x; v[1] = (bf16)a.y; v[2] = (bf16)a.z; v[3] = (bf16)a.w;
  v[4] = (bf16)b.x; v[5] = (bf16)b.y; v[6] = (bf16)b.z; v[7] = (bf16)b.w;
  *(bf16x8*)(xb + i) = v;
}

// ---------------- W [K][N] fp32 -> WT [N][K] bf16 ----------------
__global__ __launch_bounds__(256) void k_tw(const float* __restrict__ W0,
                                            const float* __restrict__ W1,
                                            const float* __restrict__ W2,
                                            const float* __restrict__ W3,
                                            bf16* __restrict__ WT) {
  __shared__ float tile[32][33];
  const float* W = (blockIdx.z == 0) ? W0 : (blockIdx.z == 1) ? W1
                  : (blockIdx.z == 2) ? W2 : W3;
  bf16* out = WT + (size_t)blockIdx.z * Cn * Cn;
  int tx = threadIdx.x & 31, ty = threadIdx.x >> 5;  // 32 x 8
  int gx = blockIdx.x * 32 + tx;   // n
  int gy = blockIdx.y * 32;        // k
#pragma unroll
  for (int j = 0; j < 32; j += 8)
    tile[ty + j][tx] = W[(size_t)(gy + ty + j) * Cn + gx];
  __syncthreads();
  int ox = blockIdx.y * 32 + tx;   // k
  int oy = blockIdx.x * 32;        // n
#pragma unroll
  for (int j = 0; j < 32; j += 8)
    out[(size_t)(oy + ty + j) * Cn + ox] = (bf16)tile[tx][ty + j];
}

// ---- GEMM core loop (shared): acc += A_tile @ B_tile^T over K=1024 ----
// ---------------- fused QKV GEMM: N = 3072 (Wq|Wk|Wv stacked in WT) -------
// out = Qh base; Q at +0, K at +8388608, V at +16777216 elems, headed layout.
__global__ __launch_bounds__(256) void k_gemm_qkv(const bf16* __restrict__ A,
                                                  const bf16* __restrict__ BT,
                                                  const float* __restrict__ bq,
                                                  const float* __restrict__ bk,
                                                  const float* __restrict__ bv,
                                                  bf16* __restrict__ out,
                                                  float qscale) {
  constexpr int KD = 1024;
  __shared__ __align__(16) bf16 As[128 * 64];
  __shared__ __align__(16) bf16 Bs[128 * 64];
  const int t = threadIdx.x;
  const int w = t >> 6, l = t & 63;
  const int m0 = blockIdx.y * 128, n0 = blockIdx.x * 128;
  const int wr = (w >> 1) * 64, wc = (w & 1) * 64;
  f32x4 acc[4][4] = {};

  for (int kt = 0; kt < KD; kt += 64) {
    __syncthreads();
#pragma unroll
    for (int i = 0; i < 4; ++i) {
      int c = i * 256 + t;
      int row = c >> 3;
      int seg = (c & 7) ^ (row & 7);
      gl_lds16(A + (size_t)(m0 + row) * KD + kt + seg * 8,
               (char*)As + i * 4096 + w * 1024);
      gl_lds16(BT + (size_t)(n0 + row) * KD + kt + seg * 8,
               (char*)Bs + i * 4096 + w * 1024);
    }
    __syncthreads();
#pragma unroll
    for (int kc = 0; kc < 2; ++kc) {
      bf16x8 af[4], bg[4];
#pragma unroll
      for (int mi = 0; mi < 4; ++mi) {
        int row = wr + mi * 16 + (l & 15);
        int off = (row * 128 + kc * 64 + (l >> 4) * 16) ^ ((row & 7) << 4);
        af[mi] = *(const bf16x8*)((const char*)As + off);
      }
#pragma unroll
      for (int ni = 0; ni < 4; ++ni) {
        int row = wc + ni * 16 + (l & 15);
        int off = (row * 128 + kc * 64 + (l >> 4) * 16) ^ ((row & 7) << 4);
        bg[ni] = *(const bf16x8*)((const char*)Bs + off);
      }
#pragma unroll
      for (int mi = 0; mi < 4; ++mi)
#pragma unroll
        for (int ni = 0; ni < 4; ++ni)
          acc[mi][ni] = __builtin_amdgcn_mfma_f32_16x16x32_bf16(
              af[mi], bg[ni], acc[mi][ni], 0, 0, 0);
    }
  }
  const int q16l = l & 15;
#pragma unroll
  for (int ni = 0; ni < 4; ++ni) {
    int colBase = n0 + wc + ni * 16;           // multiple of 16
    int which = colBase >> 10;                 // 0=Q 1=K 2=V (uniform per ni)
    const float* bp = (which == 0) ? bq : (which == 1) ? bk : bv;
    float scl = (which == 0) ? qscale : 1.0f;
    float bval = bp[(colBase & 1023) + q16l];
    int hh = (colBase >> 6) & 15;
    int dd = (colBase & 63) + q16l;
    size_t obase = (size_t)which * 8388608 + (size_t)hh * (Tn * HD) + dd;
#pragma unroll
    for (int mi = 0; mi < 4; ++mi) {
#pragma unroll
      for (int r = 0; r < 4; ++r) {
        int row = m0 + wr + mi * 16 + (l >> 4) * 4 + r;
        int bb = row >> 11, tt = row & 2047;
        float v = (acc[mi][ni][r] + bval) * scl;
        out[obase + ((size_t)bb * Hn * Tn + tt) * HD] = (bf16)v;
      }
    }
  }
}

// ---------------- output projection GEMM: out fp32 flat [M][C] ----------
__global__ __launch_bounds__(256) void k_gemm_o(const bf16* __restrict__ A,
                                                const bf16* __restrict__ BT,
                                                const float* __restrict__ bias,
                                                float* __restrict__ out) {
  constexpr int KD = 1024;
  __shared__ __align__(16) bf16 As[128 * 64];
  __shared__ __align__(16) bf16 Bs[128 * 64];
  const int t = threadIdx.x;
  const int w = t >> 6, l = t & 63;
  const int m0 = blockIdx.y * 128, n0 = blockIdx.x * 128;
  const int wr = (w >> 1) * 64, wc = (w & 1) * 64;
  f32x4 acc[4][4] = {};

  for (int kt = 0; kt < KD; kt += 64) {
    __syncthreads();
#pragma unroll
    for (int i = 0; i < 4; ++i) {
      int c = i * 256 + t;
      int row = c >> 3;
      int seg = (c & 7) ^ (row & 7);
      gl_lds16(A + (size_t)(m0 + row) * KD + kt + seg * 8,
               (char*)As + i * 4096 + w * 1024);
      gl_lds16(BT + (size_t)(n0 + row) * KD + kt + seg * 8,
               (char*)Bs + i * 4096 + w * 1024);
    }
    __syncthreads();
#pragma unroll
    for (int kc = 0; kc < 2; ++kc) {
      bf16x8 af[4], bg[4];
#pragma unroll
      for (int mi = 0; mi < 4; ++mi) {
        int row = wr + mi * 16 + (l & 15);
        int off = (row * 128 + kc * 64 + (l >> 4) * 16) ^ ((row & 7) << 4);
        af[mi] = *(const bf16x8*)((const char*)As + off);
      }
#pragma unroll
      for (int ni = 0; ni < 4; ++ni) {
        int row = wc + ni * 16 + (l & 15);
        int off = (row * 128 + kc * 64 + (l >> 4) * 16) ^ ((row & 7) << 4);
        bg[ni] = *(const bf16x8*)((const char*)Bs + off);
      }
#pragma unroll
      for (int mi = 0; mi < 4; ++mi)
#pragma unroll
        for (int ni = 0; ni < 4; ++ni)
          acc[mi][ni] = __builtin_amdgcn_mfma_f32_16x16x32_bf16(
              af[mi], bg[ni], acc[mi][ni], 0, 0, 0);
    }
  }
#pragma unroll
  for (int ni = 0; ni < 4; ++ni) {
    int col = n0 + wc + ni * 16 + (l & 15);
    float bv = bias[col];
#pragma unroll
    for (int mi = 0; mi < 4; ++mi) {
#pragma unroll
      for (int r = 0; r < 4; ++r) {
        int row = m0 + wr + mi * 16 + (l >> 4) * 4 + r;
        out[(size_t)row * Cn + col] = acc[mi][ni][r] + bv;
      }
    }
  }
}

// ---------------- flash attention (causal), swapped-operand + dbuf ----------
// Q pre-scaled by 0.125*log2e -> softmax in base-2 (exp2 direct).
// LDS banks: Ks0@0  Ks1@8192  Vt0@16384  Vt1@24576  (all offsets immediate).
// All swizzled addresses decomposed as per-lane base VGPR + compile-time
// immediate via (B + C)^X = B + (C^X) when B's low-7 bits are 0.
__global__ __launch_bounds__(256) void k_attn(const bf16* __restrict__ Q,
                                              const bf16* __restrict__ K,
                                              const bf16* __restrict__ V,
                                              bf16* __restrict__ Y) {
  __shared__ __align__(16) char smem[32768];
  const int t = threadIdx.x, w = t >> 6, l = t & 63;
  const int g = l >> 4, q16 = l & 15;
  const int wg = blockIdx.x;
  const int bh = wg & 63;                      // low bits -> XCD pinning
  const int qtile = 31 - (wg >> 6);            // heavy tiles first
  const size_t base = (size_t)bh * Tn * HD;
  const bf16* Qh = Q + base;
  const bf16* Vh = V + base;
  const int qbase = qtile * 64 + w * 16;
  const int qg = qbase + q16;

  bf16x8 aq[2];
#pragma unroll
  for (int kc = 0; kc < 2; ++kc)
    aq[kc] = *(const bf16x8*)(Qh + (size_t)qg * HD + kc * 32 + g * 8);

  // LDS address bases (bytes, per-lane, loop-invariant)
  const int xm = (q16 & 7) << 4;
  const int qkB0 = q16 * 128 + ((g * 16) ^ xm);        // kc/vkc = 0
  const int qkB1 = q16 * 128 + ((64 + g * 16) ^ xm);   // kc/vkc = 1
  const int innerL = (l >> 5) * 64 + ((l & 15) >> 2) * 16 +
                     (((l >> 4) & 1) * 4 + (l & 3)) * 2;
  int stb[8];
#pragma unroll
  for (int j = 0; j < 8; ++j)
    stb[j] = w * 1024 + j * 128 + (innerL ^ (j << 4));

  // global staging pointers (advance 4096 elems per KV tile)
  const bf16* kP = K + base +
                   (size_t)((t >> 3) * HD + (((t & 7) ^ ((t >> 3) & 7)) * 8));
  const bf16* vP = Vh + (size_t)l * HD + w * 8;  // vv0 @ +0, vv1 @ +32

  f32x4 yacc[4] = {};
  float m_ = -1e30f, l_ = 0.f;
  const int nt = qtile + 1;

#define STAGE_K(KBUF)                                       \
  {                                                         \
    gl_lds16(kP, smem + (KBUF) + w * 1024);                 \
    gl_lds16(kP + 2048, smem + (KBUF) + 4096 + w * 1024);   \
    kP += 4096;                                             \
  }
#define WRITE_V(VBUF, a0, a1)                               \
  {                                                         \
    _Pragma("unroll") for (int j = 0; j < 8; ++j) {         \
      *(bf16*)(smem + (VBUF) + stb[j]) = a0[j];             \
      *(bf16*)(smem + (VBUF) + 4096 + stb[j]) = a1[j];      \
    }                                                       \
  }
#define COMPUTE(KBUF, VBUF, DOMASK)                                          \
  {                                                                          \
    f32x4 s[4] = {};                                                         \
    __builtin_amdgcn_s_setprio(1);                                           \
    _Pragma("unroll") for (int nj = 0; nj < 4; ++nj) {                       \
      bf16x8 ak0 = *(const bf16x8*)(smem + (KBUF) + qkB0 + nj * 2048);       \
      s[nj] = __builtin_amdgcn_mfma_f32_16x16x32_bf16(ak0, aq[0], s[nj], 0, 0, 0); \
      bf16x8 ak1 = *(const bf16x8*)(smem + (KBUF) + qkB1 + nj * 2048);       \
      s[nj] = __builtin_amdgcn_mfma_f32_16x16x32_bf16(ak1, aq[1], s[nj], 0, 0, 0); \
    }                                                                        \
    __builtin_amdgcn_s_setprio(0);                                           \
    if (DOMASK) { /* last tile only: kv-in-tile = nj*16+g*4+r vs w*16+q16 */ \
      _Pragma("unroll") for (int nj = 0; nj < 4; ++nj)                       \
        _Pragma("unroll") for (int r = 0; r < 4; ++r)                        \
          if (nj * 16 + g * 4 + r > w * 16 + q16) s[nj][r] = -1e30f;         \
    }                                                                        \
    float mx = fmaxf(fmaxf(fmaxf(s[0][0], s[0][1]), fmaxf(s[0][2], s[0][3])),\
                     fmaxf(fmaxf(s[1][0], s[1][1]), fmaxf(s[1][2], s[1][3])));\
    mx = fmaxf(mx, fmaxf(fmaxf(fmaxf(s[2][0], s[2][1]), fmaxf(s[2][2], s[2][3])),\
                         fmaxf(fmaxf(s[3][0], s[3][1]), fmaxf(s[3][2], s[3][3]))));\
    mx = fmaxf(mx, __shfl_xor(mx, 16));                                      \
    mx = fmaxf(mx, __shfl_xor(mx, 32));                                      \
    float mn = fmaxf(m_, mx);                                                \
    float fac = __builtin_amdgcn_exp2f(m_ - mn);                             \
    m_ = mn;                                                                 \
    float rs = 0.f;                                                          \
    _Pragma("unroll") for (int nj = 0; nj < 4; ++nj)                         \
      _Pragma("unroll") for (int r = 0; r < 4; ++r) {                        \
        float pv = __builtin_amdgcn_exp2f(s[nj][r] - mn);                    \
        s[nj][r] = pv;                                                       \
        rs += pv;                                                            \
      }                                                                      \
    rs += __shfl_xor(rs, 16);                                                \
    rs += __shfl_xor(rs, 32);                                                \
    l_ = l_ * fac + rs;                                                      \
    _Pragma("unroll") for (int ni = 0; ni < 4; ++ni)                         \
      _Pragma("unroll") for (int r = 0; r < 4; ++r) yacc[ni][r] *= fac;      \
    __builtin_amdgcn_s_setprio(1);                                           \
    _Pragma("unroll") for (int vkc = 0; vkc < 2; ++vkc) {                    \
      bf16x8 pb;                                                             \
      _Pragma("unroll") for (int j = 0; j < 4; ++j) {                        \
        pb[j] = (bf16)s[2 * vkc][j];                                         \
        pb[4 + j] = (bf16)s[2 * vkc + 1][j];                                 \
      }                                                                      \
      int vb = (vkc == 0) ? qkB0 : qkB1;                                     \
      _Pragma("unroll") for (int ni = 0; ni < 4; ++ni) {                     \
        bf16x8 va = *(const bf16x8*)(smem + (VBUF) + vb + ni * 2048);        \
        yacc[ni] = __builtin_amdgcn_mfma_f32_16x16x32_bf16(va, pb, yacc[ni], 0, 0, 0); \
      }                                                                      \
    }                                                                        \
    __builtin_amdgcn_s_setprio(0);                                           \
  }

  // prologue: tile 0 -> bank 0
  STAGE_K(0);
  {
    bf16x8 a0 = *(const bf16x8*)vP;
    bf16x8 a1 = *(const bf16x8*)(vP + 32);
    vP += 4096;
    WRITE_V(16384, a0, a1);
  }

  int it = 0;
  for (;;) {
    // even phase: compute bank0, prefetch -> bank1
    __syncthreads();
    bool more = (it + 1) < nt;
    bf16x8 a0, a1;
    if (more) {
      STAGE_K(8192);
      a0 = *(const bf16x8*)vP;
      a1 = *(const bf16x8*)(vP + 32);
      vP += 4096;
    }
    COMPUTE(0, 16384, !more);
    if (more) WRITE_V(24576, a0, a1);
    if (++it >= nt) break;

    // odd phase: compute bank1, prefetch -> bank0
    __syncthreads();
    more = (it + 1) < nt;
    if (more) {
      STAGE_K(0);
      a0 = *(const bf16x8*)vP;
      a1 = *(const bf16x8*)(vP + 32);
      vP += 4096;
    }
    COMPUTE(8192, 24576, !more);
    if (more) WRITE_V(16384, a0, a1);
    if (++it >= nt) break;
  }
#undef STAGE_K
#undef WRITE_V
#undef COMPUTE

  // epilogue: lane owns q = qg; d = ni*16 + g*4 + r (contiguous in r)
  const int hh = bh & 15, bb = bh >> 4;
  float inv = 1.f / l_;
#pragma unroll
  for (int ni = 0; ni < 4; ++ni) {
    bf16x4 o;
#pragma unroll
    for (int r = 0; r < 4; ++r) o[r] = (bf16)(yacc[ni][r] * inv);
    int d0 = ni * 16 + g * 4;
    *(bf16x4*)&Y[(size_t)(bb * Tn + qg) * Cn + hh * HD + d0] = o;
  }
}

extern "C" void kernel_launch(void* const* d_in, const int* in_sizes, int n_in,
                              void* d_out, int out_size, void* d_ws,
                              size_t ws_size, hipStream_t stream) {
  const float* x  = (const float*)d_in[0];
  const float* Wq = (const float*)d_in[1];
  const float* bq = (const float*)d_in[2];
  const float* Wk = (const float*)d_in[3];
  const float* bk = (const float*)d_in[4];
  const float* Wv = (const float*)d_in[5];
  const float* bv = (const float*)d_in[6];
  const float* Wo = (const float*)d_in[7];
  const float* bo = (const float*)d_in[8];
  char* ws = (char*)d_ws;
  bf16* xb = (bf16*)ws;                          // 16MB, reused as y
  bf16* WT = (bf16*)(ws + (size_t)(16 << 20));   // 8MB (4 x 1M elems)
  bf16* Qh = (bf16*)(ws + (size_t)(24 << 20));   // 16MB (K,V follow at +16/+32MB)
  bf16* Kh = (bf16*)(ws + (size_t)(40 << 20));
  bf16* Vh = (bf16*)(ws + (size_t)(56 << 20));
  float* out = (float*)d_out;                    // reference output is fp32

  const float QSCALE = 0.125f * 1.44269504088896f;  // 1/sqrt(64) * log2(e)

  k_cvt_x<<<4096, 256, 0, stream>>>(x, xb);
  k_tw<<<dim3(32, 32, 4), 256, 0, stream>>>(Wq, Wk, Wv, Wo, WT);
  k_gemm_qkv<<<dim3(24, 64), 256, 0, stream>>>(xb, WT, bq, bk, bv, Qh, QSCALE);
  k_attn<<<2048, 256, 0, stream>>>(Qh, Kh, Vh, xb);
  k_gemm_o<<<dim3(8, 64), 256, 0, stream>>>(xb, WT + (3u << 20), bo, out);
}